// Round 4
// baseline (632.884 us; speedup 1.0000x reference)
//
#include <hip/hip_runtime.h>
#include <hip/hip_bf16.h>
#include <hip/hip_fp16.h>
#include <math.h>
#include <stdint.h>

// GNN relation module, restructured:
//   h_e = P[src] + Q[dst]  (node-level GEMMs instead of edge-level)
//   P = [x|box|1] @ [Wa; Wc; 0],  Q = [x|box|1] @ [Wb-Wa; -Wc; b]
// GEMMs run on MFMA via bf16 hi/lo split (3-term emulation).
// PQ stored fp16 (error ~5e-4 << threshold): halves gather traffic.
// segment_max commutes with BN+ReLU (slope rstd*gamma >= 0): max raw h per
// dst node, then normalize node-level maxima. Empty segments via counts==0.
// edge_pass: 1 node/wave, 8 row-gathers in flight (clamped-duplicate tail:
// duplicates are max-neutral; sum/sq masked by uniform select).

constexpr int NNODE = 16384;
constexpr int NEDGE = 262144;
constexpr int CD    = 256;
constexpr float EPSB = 1e-5f;

typedef __attribute__((ext_vector_type(8))) short bf16x8;
typedef __attribute__((ext_vector_type(8))) unsigned short u16x8;
typedef __attribute__((ext_vector_type(4))) float f32x4;
typedef __attribute__((ext_vector_type(4))) _Float16 h16x4;

__device__ inline unsigned short bf_hi_rne(float f) {
  unsigned int u = __float_as_uint(f);
  u += 0x7fffu + ((u >> 16) & 1u);
  return (unsigned short)(u >> 16);
}

// ---------------- weight prep: transposed combined matrices, bf16 hi/lo ----------------
__global__ void build_wt(const float* __restrict__ W, const float* __restrict__ b,
                         unsigned short* __restrict__ Wth, unsigned short* __restrict__ Wtl,
                         int has_box) {
  int k = threadIdx.x;          // 0..319
  int n = blockIdx.x;           // 0..511
  if (k >= 288) return;
  float v = 0.0f;
  if (n < 256) {                // P part
    if (k < 256)      v = W[k * 256 + n];
    else if (k < 263) v = has_box ? W[(512 + (k - 256)) * 256 + n] : 0.0f;
  } else {                      // Q part
    int n2 = n - 256;
    if (k < 256)      v = W[(256 + k) * 256 + n2] - W[k * 256 + n2];
    else if (k < 263) v = has_box ? -W[(512 + (k - 256)) * 256 + n2] : 0.0f;
    else if (k == 263) v = b[n2];
  }
  unsigned short hi = bf_hi_rne(v);
  float fh = __uint_as_float((unsigned int)hi << 16);
  Wth[n * 288 + k] = hi;
  Wtl[n * 288 + k] = bf_hi_rne(v - fh);
}

__global__ void build_wtg(const float* __restrict__ Wg, const float* __restrict__ bg,
                          unsigned short* __restrict__ Wth, unsigned short* __restrict__ Wtl) {
  int k = threadIdx.x;
  int n = blockIdx.x;
  if (k >= 288) return;
  float v = 0.0f;
  if (k < 263)       v = Wg[k * 256 + n];
  else if (k == 263) v = bg[n];
  unsigned short hi = bf_hi_rne(v);
  float fh = __uint_as_float((unsigned int)hi << 16);
  Wth[n * 288 + k] = hi;
  Wtl[n * 288 + k] = bf_hi_rne(v - fh);
}

// boxf[n][0..7] = {rois[n][0..6], 1.0}
__global__ void build_boxf(const float* __restrict__ rois, float* __restrict__ boxf) {
  int n = blockIdx.x * 256 + threadIdx.x;
  float v[8];
#pragma unroll
  for (int j = 0; j < 7; j++) v[j] = rois[n * 7 + j];
  v[7] = 1.0f;
  *(float4*)(boxf + (size_t)n * 8)     = make_float4(v[0], v[1], v[2], v[3]);
  *(float4*)(boxf + (size_t)n * 8 + 4) = make_float4(v[4], v[5], v[6], v[7]);
}

// ---------------- CSR build (counting sort by dst) ----------------
__global__ void hist_kernel(const int* __restrict__ dst, int* __restrict__ counts) {
  int e = blockIdx.x * 256 + threadIdx.x;
  atomicAdd(&counts[dst[e]], 1);
}

__global__ __launch_bounds__(1024) void scan_kernel(const int* __restrict__ counts,
                                                    int* __restrict__ offsets,
                                                    int* __restrict__ cursor) {
  __shared__ int ssum[1024];
  int t = threadIdx.x;
  int base = t * 16;
  int loc[16];
  int s = 0;
#pragma unroll
  for (int i = 0; i < 16; i++) { loc[i] = s; s += counts[base + i]; }
  ssum[t] = s;
  __syncthreads();
  for (int off = 1; off < 1024; off <<= 1) {
    int v = (t >= off) ? ssum[t - off] : 0;
    __syncthreads();
    ssum[t] += v;
    __syncthreads();
  }
  int excl = (t > 0) ? ssum[t - 1] : 0;
#pragma unroll
  for (int i = 0; i < 16; i++) {
    int o = excl + loc[i];
    offsets[base + i] = o;
    cursor[base + i]  = o;
  }
  if (t == 1023) offsets[NNODE] = excl + s;
}

__global__ void scatter_kernel(const int* __restrict__ src, const int* __restrict__ dst,
                               int* __restrict__ cursor, int* __restrict__ csr_src) {
  int e = blockIdx.x * 256 + threadIdx.x;
  int p = atomicAdd(&cursor[dst[e]], 1);
  csr_src[p] = src[e];
}

// ---------------- MFMA GEMM: out[NN,Nw] = [X(256)|box(7)|1|pad] @ Wt^T ----------------
// 128x128 tile, 4 waves (2x2 of 64x64), K padded to 288 (9 steps of 32).
// LINEAR LDS [row][64B]: fragment reads cover whole rows via the 4 lane-groups
// -> conflict-free. half_out: write fp16 (PQ), else fp32.
__global__ __launch_bounds__(256) void gemm_mfma(
    const float* __restrict__ X, int xstride,
    const float* __restrict__ boxf,
    const unsigned short* __restrict__ Wth, const unsigned short* __restrict__ Wtl,
    float* __restrict__ out, int Nw, int half_out) {
  __shared__ alignas(16) char lds[4 * 8192];   // Ahi | Alo | Bhi | Blo, 128 rows x 64B
  const int tid  = threadIdx.x;
  const int lane = tid & 63;
  const int wave = tid >> 6;
  const int wm = wave >> 1, wn = wave & 1;
  const int m0 = blockIdx.x * 128;
  const int n0 = blockIdx.y * 128;
  const int srow0 = tid >> 2;
  const int sc8   = tid & 3;

  f32x4 acc[4][4];
#pragma unroll
  for (int i = 0; i < 4; i++)
#pragma unroll
    for (int j = 0; j < 4; j++) acc[i][j] = (f32x4)0.0f;

  float a_f[2][8];
  u16x8 b_h[2], b_l[2];

  auto load_global = [&](int kt) {
#pragma unroll
    for (int p = 0; p < 2; p++) {
      int row = p * 64 + srow0;
      if (kt < 8) {
        const float* src = X + (size_t)(m0 + row) * xstride + kt * 32 + sc8 * 8;
        float4 v0 = *(const float4*)src;
        float4 v1 = *(const float4*)(src + 4);
        a_f[p][0] = v0.x; a_f[p][1] = v0.y; a_f[p][2] = v0.z; a_f[p][3] = v0.w;
        a_f[p][4] = v1.x; a_f[p][5] = v1.y; a_f[p][6] = v1.z; a_f[p][7] = v1.w;
      } else if (sc8 == 0) {
        float4 v0 = *(const float4*)(boxf + (size_t)(m0 + row) * 8);
        float4 v1 = *(const float4*)(boxf + (size_t)(m0 + row) * 8 + 4);
        a_f[p][0] = v0.x; a_f[p][1] = v0.y; a_f[p][2] = v0.z; a_f[p][3] = v0.w;
        a_f[p][4] = v1.x; a_f[p][5] = v1.y; a_f[p][6] = v1.z; a_f[p][7] = v1.w;
      } else {
#pragma unroll
        for (int j = 0; j < 8; j++) a_f[p][j] = 0.0f;
      }
      const size_t woff = (size_t)(n0 + row) * 288 + kt * 32 + sc8 * 8;
      b_h[p] = *(const u16x8*)(Wth + woff);
      b_l[p] = *(const u16x8*)(Wtl + woff);
    }
  };

  auto write_lds = [&]() {
#pragma unroll
    for (int p = 0; p < 2; p++) {
      int row = p * 64 + srow0;
      int off = row * 64 + 16 * sc8;
      u16x8 hi, lo;
#pragma unroll
      for (int j = 0; j < 8; j++) {
        float f = a_f[p][j];
        unsigned short h = bf_hi_rne(f);
        float fh = __uint_as_float((unsigned int)h << 16);
        hi[j] = h;
        lo[j] = bf_hi_rne(f - fh);
      }
      *(u16x8*)(lds + off)         = hi;
      *(u16x8*)(lds + 8192 + off)  = lo;
      *(u16x8*)(lds + 16384 + off) = b_h[p];
      *(u16x8*)(lds + 24576 + off) = b_l[p];
    }
  };

  load_global(0);
  const int kblk = lane >> 4;
  for (int kt = 0; kt < 9; kt++) {
    __syncthreads();
    write_lds();
    __syncthreads();
    if (kt < 8) load_global(kt + 1);

    bf16x8 ah[4], al[4];
#pragma unroll
    for (int i = 0; i < 4; i++) {
      int fm = wm * 64 + i * 16 + (lane & 15);
      int off = fm * 64 + 16 * kblk;
      ah[i] = *(const bf16x8*)(lds + off);
      al[i] = *(const bf16x8*)(lds + 8192 + off);
    }
#pragma unroll
    for (int j = 0; j < 4; j++) {
      int fn = wn * 64 + j * 16 + (lane & 15);
      int off = fn * 64 + 16 * kblk;
      bf16x8 bh = *(const bf16x8*)(lds + 16384 + off);
      bf16x8 bl = *(const bf16x8*)(lds + 24576 + off);
#pragma unroll
      for (int i = 0; i < 4; i++) {
        acc[i][j] = __builtin_amdgcn_mfma_f32_16x16x32_bf16(bh, ah[i], acc[i][j], 0, 0, 0);
        acc[i][j] = __builtin_amdgcn_mfma_f32_16x16x32_bf16(bh, al[i], acc[i][j], 0, 0, 0);
        acc[i][j] = __builtin_amdgcn_mfma_f32_16x16x32_bf16(bl, ah[i], acc[i][j], 0, 0, 0);
      }
    }
  }
#pragma unroll
  for (int i = 0; i < 4; i++) {
    int m = m0 + wm * 64 + i * 16 + (lane & 15);
#pragma unroll
    for (int j = 0; j < 4; j++) {
      int n = n0 + wn * 64 + j * 16 + (lane >> 4) * 4;
      if (half_out) {
        h16x4 o;
        o[0] = (_Float16)acc[i][j].x; o[1] = (_Float16)acc[i][j].y;
        o[2] = (_Float16)acc[i][j].z; o[3] = (_Float16)acc[i][j].w;
        *(h16x4*)((_Float16*)out + (size_t)m * Nw + n) = o;
      } else {
        *(f32x4*)(out + (size_t)m * Nw + n) = acc[i][j];
      }
    }
  }
}

// ---------------- edge pass: 1 node/wave, 8 gathers in flight ----------------
constexpr int CHUNK = 8;
__global__ __launch_bounds__(256) void edge_pass(
    const _Float16* __restrict__ PQ,   // [NN][512] fp16 (P 0:256, Q 256:512)
    const int* __restrict__ offsets, const int* __restrict__ csr_src,
    float* __restrict__ M, float* __restrict__ psum, float* __restrict__ psq) {
  __shared__ float red[2][4][256];
  const int tid = threadIdx.x;
  const int wave = tid >> 6, lane = tid & 63;
  const int c4 = lane * 4;
  float sum0 = 0.f, sum1 = 0.f, sum2 = 0.f, sum3 = 0.f;
  float sq0 = 0.f, sq1 = 0.f, sq2 = 0.f, sq3 = 0.f;
  const int d = blockIdx.x * 4 + wave;
  const int beg = offsets[d], end = offsets[d + 1];

  if (beg < end) {
    h16x4 qv = *(const h16x4*)(PQ + (size_t)d * 512 + 256 + c4);
    const float q0 = (float)qv[0], q1 = (float)qv[1], q2 = (float)qv[2], q3 = (float)qv[3];
    float mx0 = -INFINITY, mx1 = -INFINITY, mx2 = -INFINITY, mx3 = -INFINITY;

    for (int e = beg; e < end; e += CHUNK) {
      const int nlive = end - e;
      int idx[CHUNK];
#pragma unroll
      for (int i = 0; i < CHUNK; i++) {
        int ei = e + i;
        idx[i] = csr_src[ei < end ? ei : end - 1];   // clamped duplicate (max-neutral)
      }
      h16x4 pv[CHUNK];
#pragma unroll
      for (int i = 0; i < CHUNK; i++)
        pv[i] = *(const h16x4*)(PQ + (size_t)idx[i] * 512 + c4);
#pragma unroll
      for (int i = 0; i < CHUNK; i++) {
        float h0 = (float)pv[i][0] + q0;
        float h1 = (float)pv[i][1] + q1;
        float h2 = (float)pv[i][2] + q2;
        float h3 = (float)pv[i][3] + q3;
        mx0 = fmaxf(mx0, h0); mx1 = fmaxf(mx1, h1);
        mx2 = fmaxf(mx2, h2); mx3 = fmaxf(mx3, h3);
        const bool live = i < nlive;                 // wave-uniform select
        float z0 = live ? h0 : 0.f, z1 = live ? h1 : 0.f;
        float z2 = live ? h2 : 0.f, z3 = live ? h3 : 0.f;
        sum0 += z0; sum1 += z1; sum2 += z2; sum3 += z3;
        sq0 = fmaf(z0, z0, sq0); sq1 = fmaf(z1, z1, sq1);
        sq2 = fmaf(z2, z2, sq2); sq3 = fmaf(z3, z3, sq3);
      }
    }
    *(float4*)(M + (size_t)d * 256 + c4) = make_float4(mx0, mx1, mx2, mx3);
  }

  red[0][wave][c4]     = sum0; red[0][wave][c4 + 1] = sum1;
  red[0][wave][c4 + 2] = sum2; red[0][wave][c4 + 3] = sum3;
  red[1][wave][c4]     = sq0;  red[1][wave][c4 + 1] = sq1;
  red[1][wave][c4 + 2] = sq2;  red[1][wave][c4 + 3] = sq3;
  __syncthreads();
  int c = tid;
  float ts = red[0][0][c] + red[0][1][c] + red[0][2][c] + red[0][3][c];
  float tq = red[1][0][c] + red[1][1][c] + red[1][2][c] + red[1][3][c];
  atomicAdd(&psum[c], ts);
  atomicAdd(&psq[c], tq);
}

// ---------------- BN stats over dense rows (for x0) ----------------
__global__ void stats_dense(const float* __restrict__ H,
                            float* __restrict__ psum, float* __restrict__ psq) {
  int c  = threadIdx.x;
  int r0 = blockIdx.x * 16;
  float sum = 0.f, sq = 0.f;
  for (int r = r0; r < r0 + 16; r++) {
    float h = H[r * CD + c];
    sum += h;
    sq  += h * h;
  }
  atomicAdd(&psum[c], sum);
  atomicAdd(&psq[c], sq);
}

__global__ void finalize_stats(const float* __restrict__ psum, const float* __restrict__ psq,
                               float invcount, float* __restrict__ mu, float* __restrict__ rstd) {
  int c = threadIdx.x;
  float m = psum[c] * invcount;
  float v = psq[c] * invcount - m * m;
  v = fmaxf(v, 0.0f);
  mu[c]   = m;
  rstd[c] = 1.0f / sqrtf(v + EPSB);
}

__global__ void normalize_write(const float* __restrict__ H, const int* __restrict__ counts,
                                const float* __restrict__ mu, const float* __restrict__ rstd,
                                const float* __restrict__ gamma, const float* __restrict__ beta,
                                float* __restrict__ out, int col0) {
  int c  = threadIdx.x;
  int n0 = blockIdx.x * 8;
  float mc = mu[c], rc = rstd[c], gc = gamma[c], bc = beta[c];
  for (int n = n0; n < n0 + 8; n++) {
    float v = 0.0f;
    if (!counts || counts[n] != 0) {
      float h = H[n * CD + c];
      v = fmaxf((h - mc) * rc * gc + bc, 0.0f);
    }
    out[n * 1024 + col0 + c] = v;
  }
}

// ---------------- launch ----------------
extern "C" void kernel_launch(void* const* d_in, const int* in_sizes, int n_in,
                              void* d_out, int out_size, void* d_ws, size_t ws_size,
                              hipStream_t stream) {
  const float* pf    = (const float*)d_in[0];
  const float* rois  = (const float*)d_in[1];
  const int*   esrc  = (const int*)d_in[2];
  const int*   edst  = (const int*)d_in[3];
  const float* Wg    = (const float*)d_in[4];
  const float* bg    = (const float*)d_in[5];
  const float* gg    = (const float*)d_in[6];
  const float* betag = (const float*)d_in[7];
  const float* Wl[3]  = {(const float*)d_in[8],  (const float*)d_in[12], (const float*)d_in[16]};
  const float* bl[3]  = {(const float*)d_in[9],  (const float*)d_in[13], (const float*)d_in[17]};
  const float* gl[3]  = {(const float*)d_in[10], (const float*)d_in[14], (const float*)d_in[18]};
  const float* bel[3] = {(const float*)d_in[11], (const float*)d_in[15], (const float*)d_in[19]};
  float* out = (float*)d_out;

  // workspace layout (~38 MB)
  float* ws    = (float*)d_ws;
  _Float16* PQ = (_Float16*)ws;                       // NN*512 fp16
  float* Mbuf  = ws + (size_t)NNODE * 256;            // NN*256 f32
  float* psum  = Mbuf + (size_t)NNODE * CD;
  float* psq   = psum + CD;
  float* mu    = psq + CD;
  float* rstd  = mu + CD;
  float* boxf  = rstd + CD;                           // NN*8
  unsigned short* wt = (unsigned short*)(boxf + (size_t)NNODE * 8);
  unsigned short* wtg_h = wt + 3 * 2 * 512 * 288;     // per layer: hi|lo [512*288]
  unsigned short* wtg_l = wtg_h + 256 * 288;
  int* counts  = (int*)(wtg_l + 256 * 288);
  int* offsets = counts + NNODE;
  int* cursor  = offsets + NNODE + 1;
  int* csr     = cursor + NNODE;

  hipMemsetAsync(counts, 0, NNODE * sizeof(int), stream);
  build_boxf<<<NNODE / 256, 256, 0, stream>>>(rois, boxf);
  build_wtg<<<256, 320, 0, stream>>>(Wg, bg, wtg_h, wtg_l);
  for (int l = 0; l < 3; l++)
    build_wt<<<512, 320, 0, stream>>>(Wl[l], bl[l],
                                      wt + l * 2 * 512 * 288,
                                      wt + l * 2 * 512 * 288 + 512 * 288,
                                      l == 0 ? 1 : 0);
  hist_kernel<<<NEDGE / 256, 256, 0, stream>>>(edst, counts);
  scan_kernel<<<1, 1024, 0, stream>>>(counts, offsets, cursor);
  scatter_kernel<<<NEDGE / 256, 256, 0, stream>>>(esrc, edst, cursor, csr);

  // x0 = BN-ReLU([pf|box|1] @ Wg+bg)  (fp32 out)
  hipMemsetAsync(psum, 0, 2 * CD * sizeof(float), stream);
  {
    dim3 g(NNODE / 128, 256 / 128);
    gemm_mfma<<<g, 256, 0, stream>>>(pf, CD, boxf, wtg_h, wtg_l, Mbuf, CD, 0);
  }
  stats_dense<<<NNODE / 16, 256, 0, stream>>>(Mbuf, psum, psq);
  finalize_stats<<<1, 256, 0, stream>>>(psum, psq, 1.0f / NNODE, mu, rstd);
  normalize_write<<<NNODE / 8, 256, 0, stream>>>(Mbuf, nullptr, mu, rstd, gg, betag, out, 0);

  // three EdgeConv layers
  for (int l = 0; l < 3; l++) {
    dim3 g(NNODE / 128, 512 / 128);
    gemm_mfma<<<g, 256, 0, stream>>>(out + l * CD, 1024, boxf,
                                     wt + l * 2 * 512 * 288,
                                     wt + l * 2 * 512 * 288 + 512 * 288,
                                     (float*)PQ, 512, 1);
    hipMemsetAsync(psum, 0, 2 * CD * sizeof(float), stream);
    edge_pass<<<NNODE / 4, 256, 0, stream>>>(PQ, offsets, csr, Mbuf, psum, psq);
    finalize_stats<<<1, 256, 0, stream>>>(psum, psq, 1.0f / NEDGE, mu, rstd);
    normalize_write<<<NNODE / 8, 256, 0, stream>>>(Mbuf, counts, mu, rstd, gl[l], bel[l],
                                                   out, (l + 1) * CD);
  }
}

// Round 5
// 503.957 us; speedup vs baseline: 1.2558x; 1.2558x over previous
//
#include <hip/hip_runtime.h>
#include <hip/hip_bf16.h>
#include <hip/hip_fp16.h>
#include <math.h>
#include <stdint.h>

// GNN relation module, restructured:
//   h_e = P[src] + Q[dst]  (node-level GEMMs instead of edge-level)
//   P = [x|box|1] @ [Wa; Wc; 0],  Q = [x|box|1] @ [Wb-Wa; -Wc; b]
// GEMMs run on MFMA via bf16 hi/lo split (3-term emulation).
// PQ stored fp16: halves gather footprint (P-half = 8 MB, L3-resident).
// edge_pass v5: half-wave per edge — one dwordx4 gather instruction serves
// 2 edges (1 KB, 16 lines); 4 gathers in flight per wave; 2048 blocks keeps
// stats-atomic fan-in at the proven round-3 level.
// segment_max commutes with BN+ReLU (slope rstd*gamma >= 0): max raw h per
// dst node, then normalize node-level maxima. Empty segments via counts==0.

constexpr int NNODE = 16384;
constexpr int NEDGE = 262144;
constexpr int CD    = 256;
constexpr float EPSB = 1e-5f;

typedef __attribute__((ext_vector_type(8))) short bf16x8;
typedef __attribute__((ext_vector_type(8))) unsigned short u16x8;
typedef __attribute__((ext_vector_type(4))) float f32x4;
typedef __attribute__((ext_vector_type(4))) _Float16 h16x4;
typedef __attribute__((ext_vector_type(8))) _Float16 h16x8;

__device__ inline unsigned short bf_hi_rne(float f) {
  unsigned int u = __float_as_uint(f);
  u += 0x7fffu + ((u >> 16) & 1u);
  return (unsigned short)(u >> 16);
}

// ---------------- weight prep: transposed combined matrices, bf16 hi/lo ----------------
__global__ void build_wt(const float* __restrict__ W, const float* __restrict__ b,
                         unsigned short* __restrict__ Wth, unsigned short* __restrict__ Wtl,
                         int has_box) {
  int k = threadIdx.x;          // 0..319
  int n = blockIdx.x;           // 0..511
  if (k >= 288) return;
  float v = 0.0f;
  if (n < 256) {                // P part
    if (k < 256)      v = W[k * 256 + n];
    else if (k < 263) v = has_box ? W[(512 + (k - 256)) * 256 + n] : 0.0f;
  } else {                      // Q part
    int n2 = n - 256;
    if (k < 256)      v = W[(256 + k) * 256 + n2] - W[k * 256 + n2];
    else if (k < 263) v = has_box ? -W[(512 + (k - 256)) * 256 + n2] : 0.0f;
    else if (k == 263) v = b[n2];
  }
  unsigned short hi = bf_hi_rne(v);
  float fh = __uint_as_float((unsigned int)hi << 16);
  Wth[n * 288 + k] = hi;
  Wtl[n * 288 + k] = bf_hi_rne(v - fh);
}

__global__ void build_wtg(const float* __restrict__ Wg, const float* __restrict__ bg,
                          unsigned short* __restrict__ Wth, unsigned short* __restrict__ Wtl) {
  int k = threadIdx.x;
  int n = blockIdx.x;
  if (k >= 288) return;
  float v = 0.0f;
  if (k < 263)       v = Wg[k * 256 + n];
  else if (k == 263) v = bg[n];
  unsigned short hi = bf_hi_rne(v);
  float fh = __uint_as_float((unsigned int)hi << 16);
  Wth[n * 288 + k] = hi;
  Wtl[n * 288 + k] = bf_hi_rne(v - fh);
}

// boxf[n][0..7] = {rois[n][0..6], 1.0}
__global__ void build_boxf(const float* __restrict__ rois, float* __restrict__ boxf) {
  int n = blockIdx.x * 256 + threadIdx.x;
  float v[8];
#pragma unroll
  for (int j = 0; j < 7; j++) v[j] = rois[n * 7 + j];
  v[7] = 1.0f;
  *(float4*)(boxf + (size_t)n * 8)     = make_float4(v[0], v[1], v[2], v[3]);
  *(float4*)(boxf + (size_t)n * 8 + 4) = make_float4(v[4], v[5], v[6], v[7]);
}

// ---------------- CSR build (counting sort by dst) ----------------
__global__ void hist_kernel(const int* __restrict__ dst, int* __restrict__ counts) {
  int e = blockIdx.x * 256 + threadIdx.x;
  atomicAdd(&counts[dst[e]], 1);
}

__global__ __launch_bounds__(1024) void scan_kernel(const int* __restrict__ counts,
                                                    int* __restrict__ offsets,
                                                    int* __restrict__ cursor) {
  __shared__ int ssum[1024];
  int t = threadIdx.x;
  int base = t * 16;
  int loc[16];
  int s = 0;
#pragma unroll
  for (int i = 0; i < 16; i++) { loc[i] = s; s += counts[base + i]; }
  ssum[t] = s;
  __syncthreads();
  for (int off = 1; off < 1024; off <<= 1) {
    int v = (t >= off) ? ssum[t - off] : 0;
    __syncthreads();
    ssum[t] += v;
    __syncthreads();
  }
  int excl = (t > 0) ? ssum[t - 1] : 0;
#pragma unroll
  for (int i = 0; i < 16; i++) {
    int o = excl + loc[i];
    offsets[base + i] = o;
    cursor[base + i]  = o;
  }
  if (t == 1023) offsets[NNODE] = excl + s;
}

__global__ void scatter_kernel(const int* __restrict__ src, const int* __restrict__ dst,
                               int* __restrict__ cursor, int* __restrict__ csr_src) {
  int e = blockIdx.x * 256 + threadIdx.x;
  int p = atomicAdd(&cursor[dst[e]], 1);
  csr_src[p] = src[e];
}

// ---------------- MFMA GEMM: out[NN,Nw] = [X(256)|box(7)|1|pad] @ Wt^T ----------------
// 128x128 tile, 4 waves (2x2 of 64x64), K padded to 288 (9 steps of 32).
// LINEAR LDS [row][64B]: fragment reads cover whole rows via the 4 lane-groups
// -> conflict-free. half_out: write fp16 (PQ), else fp32.
__global__ __launch_bounds__(256) void gemm_mfma(
    const float* __restrict__ X, int xstride,
    const float* __restrict__ boxf,
    const unsigned short* __restrict__ Wth, const unsigned short* __restrict__ Wtl,
    float* __restrict__ out, int Nw, int half_out) {
  __shared__ alignas(16) char lds[4 * 8192];   // Ahi | Alo | Bhi | Blo, 128 rows x 64B
  const int tid  = threadIdx.x;
  const int lane = tid & 63;
  const int wave = tid >> 6;
  const int wm = wave >> 1, wn = wave & 1;
  const int m0 = blockIdx.x * 128;
  const int n0 = blockIdx.y * 128;
  const int srow0 = tid >> 2;
  const int sc8   = tid & 3;

  f32x4 acc[4][4];
#pragma unroll
  for (int i = 0; i < 4; i++)
#pragma unroll
    for (int j = 0; j < 4; j++) acc[i][j] = (f32x4)0.0f;

  float a_f[2][8];
  u16x8 b_h[2], b_l[2];

  auto load_global = [&](int kt) {
#pragma unroll
    for (int p = 0; p < 2; p++) {
      int row = p * 64 + srow0;
      if (kt < 8) {
        const float* src = X + (size_t)(m0 + row) * xstride + kt * 32 + sc8 * 8;
        float4 v0 = *(const float4*)src;
        float4 v1 = *(const float4*)(src + 4);
        a_f[p][0] = v0.x; a_f[p][1] = v0.y; a_f[p][2] = v0.z; a_f[p][3] = v0.w;
        a_f[p][4] = v1.x; a_f[p][5] = v1.y; a_f[p][6] = v1.z; a_f[p][7] = v1.w;
      } else if (sc8 == 0) {
        float4 v0 = *(const float4*)(boxf + (size_t)(m0 + row) * 8);
        float4 v1 = *(const float4*)(boxf + (size_t)(m0 + row) * 8 + 4);
        a_f[p][0] = v0.x; a_f[p][1] = v0.y; a_f[p][2] = v0.z; a_f[p][3] = v0.w;
        a_f[p][4] = v1.x; a_f[p][5] = v1.y; a_f[p][6] = v1.z; a_f[p][7] = v1.w;
      } else {
#pragma unroll
        for (int j = 0; j < 8; j++) a_f[p][j] = 0.0f;
      }
      const size_t woff = (size_t)(n0 + row) * 288 + kt * 32 + sc8 * 8;
      b_h[p] = *(const u16x8*)(Wth + woff);
      b_l[p] = *(const u16x8*)(Wtl + woff);
    }
  };

  auto write_lds = [&]() {
#pragma unroll
    for (int p = 0; p < 2; p++) {
      int row = p * 64 + srow0;
      int off = row * 64 + 16 * sc8;
      u16x8 hi, lo;
#pragma unroll
      for (int j = 0; j < 8; j++) {
        float f = a_f[p][j];
        unsigned short h = bf_hi_rne(f);
        float fh = __uint_as_float((unsigned int)h << 16);
        hi[j] = h;
        lo[j] = bf_hi_rne(f - fh);
      }
      *(u16x8*)(lds + off)         = hi;
      *(u16x8*)(lds + 8192 + off)  = lo;
      *(u16x8*)(lds + 16384 + off) = b_h[p];
      *(u16x8*)(lds + 24576 + off) = b_l[p];
    }
  };

  load_global(0);
  const int kblk = lane >> 4;
  for (int kt = 0; kt < 9; kt++) {
    __syncthreads();
    write_lds();
    __syncthreads();
    if (kt < 8) load_global(kt + 1);

    bf16x8 ah[4], al[4];
#pragma unroll
    for (int i = 0; i < 4; i++) {
      int fm = wm * 64 + i * 16 + (lane & 15);
      int off = fm * 64 + 16 * kblk;
      ah[i] = *(const bf16x8*)(lds + off);
      al[i] = *(const bf16x8*)(lds + 8192 + off);
    }
#pragma unroll
    for (int j = 0; j < 4; j++) {
      int fn = wn * 64 + j * 16 + (lane & 15);
      int off = fn * 64 + 16 * kblk;
      bf16x8 bh = *(const bf16x8*)(lds + 16384 + off);
      bf16x8 bl = *(const bf16x8*)(lds + 24576 + off);
#pragma unroll
      for (int i = 0; i < 4; i++) {
        acc[i][j] = __builtin_amdgcn_mfma_f32_16x16x32_bf16(bh, ah[i], acc[i][j], 0, 0, 0);
        acc[i][j] = __builtin_amdgcn_mfma_f32_16x16x32_bf16(bh, al[i], acc[i][j], 0, 0, 0);
        acc[i][j] = __builtin_amdgcn_mfma_f32_16x16x32_bf16(bl, ah[i], acc[i][j], 0, 0, 0);
      }
    }
  }
#pragma unroll
  for (int i = 0; i < 4; i++) {
    int m = m0 + wm * 64 + i * 16 + (lane & 15);
#pragma unroll
    for (int j = 0; j < 4; j++) {
      int n = n0 + wn * 64 + j * 16 + (lane >> 4) * 4;
      if (half_out) {
        h16x4 o;
        o[0] = (_Float16)acc[i][j].x; o[1] = (_Float16)acc[i][j].y;
        o[2] = (_Float16)acc[i][j].z; o[3] = (_Float16)acc[i][j].w;
        *(h16x4*)((_Float16*)out + (size_t)m * Nw + n) = o;
      } else {
        *(f32x4*)(out + (size_t)m * Nw + n) = acc[i][j];
      }
    }
  }
}

// ---------------- edge pass v5: half-wave per edge, 2 nodes per wave ----------------
// Lane (h = lane>>5, li = lane&31) owns fp16 columns [li*8, li*8+8) of half h's
// edge stream. One h16x8 gather instruction = 1 KB = 2 edges' 512 B rows.
constexpr int EPB = 8;   // nodes per block (4 waves x 2)
__global__ __launch_bounds__(256) void edge_pass(
    const _Float16* __restrict__ PQ,   // [NN][512] fp16 (P 0:256, Q 256:512)
    const int* __restrict__ offsets, const int* __restrict__ csr_src,
    float* __restrict__ M, float* __restrict__ psum, float* __restrict__ psq) {
  __shared__ float red[2][4][256];
  const int tid = threadIdx.x;
  const int wave = tid >> 6, lane = tid & 63;
  const int h = lane >> 5, li = lane & 31;
  const int c8 = li * 8;
  float sum[8] = {}, sq[8] = {};

  for (int nn = 0; nn < 2; nn++) {
    const int d = blockIdx.x * EPB + wave * 2 + nn;
    const int beg = offsets[d], end = offsets[d + 1];
    if (beg >= end) continue;
    h16x8 qv = *(const h16x8*)(PQ + (size_t)d * 512 + 256 + c8);
    float qf[8], mx[8];
#pragma unroll
    for (int j = 0; j < 8; j++) { qf[j] = (float)qv[j]; mx[j] = -INFINITY; }

    for (int e = beg; e < end; e += 8) {
      int idx[4];
      bool full = (e + 8 <= end);
      if (full) {
#pragma unroll
        for (int i = 0; i < 4; i++) idx[i] = csr_src[e + 2 * i + h];
        h16x8 pv[4];
#pragma unroll
        for (int i = 0; i < 4; i++)
          pv[i] = *(const h16x8*)(PQ + (size_t)idx[i] * 512 + c8);
#pragma unroll
        for (int i = 0; i < 4; i++)
#pragma unroll
          for (int j = 0; j < 8; j++) {
            float hh = (float)pv[i][j] + qf[j];
            mx[j] = fmaxf(mx[j], hh);
            sum[j] += hh;
            sq[j] = fmaf(hh, hh, sq[j]);
          }
      } else {
        bool live[4];
#pragma unroll
        for (int i = 0; i < 4; i++) {
          int ei = e + 2 * i + h;
          live[i] = ei < end;
          idx[i] = csr_src[live[i] ? ei : end - 1];   // clamped dup (max-neutral)
        }
        h16x8 pv[4];
#pragma unroll
        for (int i = 0; i < 4; i++)
          pv[i] = *(const h16x8*)(PQ + (size_t)idx[i] * 512 + c8);
#pragma unroll
        for (int i = 0; i < 4; i++)
#pragma unroll
          for (int j = 0; j < 8; j++) {
            float hh = (float)pv[i][j] + qf[j];
            mx[j] = fmaxf(mx[j], hh);
            float z = live[i] ? hh : 0.0f;
            sum[j] += z;
            sq[j] = fmaf(z, z, sq[j]);
          }
      }
    }
    // combine the two half-wave edge streams (disjoint edges, same node)
#pragma unroll
    for (int j = 0; j < 8; j++)
      mx[j] = fmaxf(mx[j], __shfl_xor(mx[j], 32));
    float4 o = (h == 0) ? make_float4(mx[0], mx[1], mx[2], mx[3])
                        : make_float4(mx[4], mx[5], mx[6], mx[7]);
    *(float4*)(M + (size_t)d * 256 + c8 + h * 4) = o;
  }

  // stats: fold halves, then per-wave LDS slot, then one atomic per column
#pragma unroll
  for (int j = 0; j < 8; j++) {
    sum[j] += __shfl_xor(sum[j], 32);
    sq[j]  += __shfl_xor(sq[j], 32);
  }
  if (h == 0) {
    float4 s0 = make_float4(sum[0], sum[1], sum[2], sum[3]);
    float4 s1 = make_float4(sum[4], sum[5], sum[6], sum[7]);
    float4 q0 = make_float4(sq[0], sq[1], sq[2], sq[3]);
    float4 q1 = make_float4(sq[4], sq[5], sq[6], sq[7]);
    *(float4*)&red[0][wave][c8]     = s0;
    *(float4*)&red[0][wave][c8 + 4] = s1;
    *(float4*)&red[1][wave][c8]     = q0;
    *(float4*)&red[1][wave][c8 + 4] = q1;
  }
  __syncthreads();
  int c = tid;
  float ts = red[0][0][c] + red[0][1][c] + red[0][2][c] + red[0][3][c];
  float tq = red[1][0][c] + red[1][1][c] + red[1][2][c] + red[1][3][c];
  atomicAdd(&psum[c], ts);
  atomicAdd(&psq[c], tq);
}

// ---------------- BN stats over dense rows (for x0) ----------------
__global__ void stats_dense(const float* __restrict__ H,
                            float* __restrict__ psum, float* __restrict__ psq) {
  int c  = threadIdx.x;
  int r0 = blockIdx.x * 16;
  float sum = 0.f, sq = 0.f;
  for (int r = r0; r < r0 + 16; r++) {
    float h = H[r * CD + c];
    sum += h;
    sq  += h * h;
  }
  atomicAdd(&psum[c], sum);
  atomicAdd(&psq[c], sq);
}

__global__ void finalize_stats(const float* __restrict__ psum, const float* __restrict__ psq,
                               float invcount, float* __restrict__ mu, float* __restrict__ rstd) {
  int c = threadIdx.x;
  float m = psum[c] * invcount;
  float v = psq[c] * invcount - m * m;
  v = fmaxf(v, 0.0f);
  mu[c]   = m;
  rstd[c] = 1.0f / sqrtf(v + EPSB);
}

__global__ void normalize_write(const float* __restrict__ H, const int* __restrict__ counts,
                                const float* __restrict__ mu, const float* __restrict__ rstd,
                                const float* __restrict__ gamma, const float* __restrict__ beta,
                                float* __restrict__ out, int col0) {
  int c  = threadIdx.x;
  int n0 = blockIdx.x * 8;
  float mc = mu[c], rc = rstd[c], gc = gamma[c], bc = beta[c];
  for (int n = n0; n < n0 + 8; n++) {
    float v = 0.0f;
    if (!counts || counts[n] != 0) {
      float h = H[n * CD + c];
      v = fmaxf((h - mc) * rc * gc + bc, 0.0f);
    }
    out[n * 1024 + col0 + c] = v;
  }
}

// ---------------- launch ----------------
extern "C" void kernel_launch(void* const* d_in, const int* in_sizes, int n_in,
                              void* d_out, int out_size, void* d_ws, size_t ws_size,
                              hipStream_t stream) {
  const float* pf    = (const float*)d_in[0];
  const float* rois  = (const float*)d_in[1];
  const int*   esrc  = (const int*)d_in[2];
  const int*   edst  = (const int*)d_in[3];
  const float* Wg    = (const float*)d_in[4];
  const float* bg    = (const float*)d_in[5];
  const float* gg    = (const float*)d_in[6];
  const float* betag = (const float*)d_in[7];
  const float* Wl[3]  = {(const float*)d_in[8],  (const float*)d_in[12], (const float*)d_in[16]};
  const float* bl[3]  = {(const float*)d_in[9],  (const float*)d_in[13], (const float*)d_in[17]};
  const float* gl[3]  = {(const float*)d_in[10], (const float*)d_in[14], (const float*)d_in[18]};
  const float* bel[3] = {(const float*)d_in[11], (const float*)d_in[15], (const float*)d_in[19]};
  float* out = (float*)d_out;

  // workspace layout (~38 MB)
  float* ws    = (float*)d_ws;
  _Float16* PQ = (_Float16*)ws;                       // NN*512 fp16
  float* Mbuf  = ws + (size_t)NNODE * 256;            // NN*256 f32
  float* psum  = Mbuf + (size_t)NNODE * CD;
  float* psq   = psum + CD;
  float* mu    = psq + CD;
  float* rstd  = mu + CD;
  float* boxf  = rstd + CD;                           // NN*8
  unsigned short* wt = (unsigned short*)(boxf + (size_t)NNODE * 8);
  unsigned short* wtg_h = wt + 3 * 2 * 512 * 288;     // per layer: hi|lo [512*288]
  unsigned short* wtg_l = wtg_h + 256 * 288;
  int* counts  = (int*)(wtg_l + 256 * 288);
  int* offsets = counts + NNODE;
  int* cursor  = offsets + NNODE + 1;
  int* csr     = cursor + NNODE;

  hipMemsetAsync(counts, 0, NNODE * sizeof(int), stream);
  build_boxf<<<NNODE / 256, 256, 0, stream>>>(rois, boxf);
  build_wtg<<<256, 320, 0, stream>>>(Wg, bg, wtg_h, wtg_l);
  for (int l = 0; l < 3; l++)
    build_wt<<<512, 320, 0, stream>>>(Wl[l], bl[l],
                                      wt + l * 2 * 512 * 288,
                                      wt + l * 2 * 512 * 288 + 512 * 288,
                                      l == 0 ? 1 : 0);
  hist_kernel<<<NEDGE / 256, 256, 0, stream>>>(edst, counts);
  scan_kernel<<<1, 1024, 0, stream>>>(counts, offsets, cursor);
  scatter_kernel<<<NEDGE / 256, 256, 0, stream>>>(esrc, edst, cursor, csr);

  // x0 = BN-ReLU([pf|box|1] @ Wg+bg)  (fp32 out)
  hipMemsetAsync(psum, 0, 2 * CD * sizeof(float), stream);
  {
    dim3 g(NNODE / 128, 256 / 128);
    gemm_mfma<<<g, 256, 0, stream>>>(pf, CD, boxf, wtg_h, wtg_l, Mbuf, CD, 0);
  }
  stats_dense<<<NNODE / 16, 256, 0, stream>>>(Mbuf, psum, psq);
  finalize_stats<<<1, 256, 0, stream>>>(psum, psq, 1.0f / NNODE, mu, rstd);
  normalize_write<<<NNODE / 8, 256, 0, stream>>>(Mbuf, nullptr, mu, rstd, gg, betag, out, 0);

  // three EdgeConv layers
  for (int l = 0; l < 3; l++) {
    dim3 g(NNODE / 128, 512 / 128);
    gemm_mfma<<<g, 256, 0, stream>>>(out + l * CD, 1024, boxf,
                                     wt + l * 2 * 512 * 288,
                                     wt + l * 2 * 512 * 288 + 512 * 288,
                                     (float*)PQ, 512, 1);
    hipMemsetAsync(psum, 0, 2 * CD * sizeof(float), stream);
    edge_pass<<<NNODE / EPB, 256, 0, stream>>>(PQ, offsets, csr, Mbuf, psum, psq);
    finalize_stats<<<1, 256, 0, stream>>>(psum, psq, 1.0f / NEDGE, mu, rstd);
    normalize_write<<<NNODE / 8, 256, 0, stream>>>(Mbuf, counts, mu, rstd, gl[l], bel[l],
                                                   out, (l + 1) * CD);
  }
}

// Round 6
// 495.161 us; speedup vs baseline: 1.2781x; 1.0178x over previous
//
#include <hip/hip_runtime.h>
#include <hip/hip_bf16.h>
#include <hip/hip_fp16.h>
#include <math.h>
#include <stdint.h>

// GNN relation module, restructured:
//   h_e = P[src] + Q[dst]  (node-level GEMMs instead of edge-level)
//   P = [x|box|1] @ [Wa; Wc; 0],  Q = [x|box|1] @ [Wb-Wa; -Wc; b]
// GEMMs on MFMA via bf16 hi/lo split (3-term). A-inputs PRE-SPLIT to bf16
// hi/lo (fused into normalize_write / convert_split) so GEMM staging is pure
// global_load_lds DMA (no VGPR round-trip, no per-tile conversion).
// PQ stored fp16. edge_pass v6: 2 nodes per wave processed CONCURRENTLY ->
// 8 x 1KB gathers in flight per round (latency-bound gather needs MLP).
// segment_max commutes with BN+ReLU (slope rstd*gamma >= 0): max raw h per
// dst node, then normalize node maxima. Empty segments via counts==0.

constexpr int NNODE = 16384;
constexpr int NEDGE = 262144;
constexpr int CD    = 256;
constexpr float EPSB = 1e-5f;

typedef __attribute__((ext_vector_type(8))) short bf16x8;
typedef __attribute__((ext_vector_type(8))) unsigned short u16x8;
typedef __attribute__((ext_vector_type(4))) float f32x4;
typedef __attribute__((ext_vector_type(4))) _Float16 h16x4;
typedef __attribute__((ext_vector_type(8))) _Float16 h16x8;

__device__ inline unsigned short bf_hi_rne(float f) {
  unsigned int u = __float_as_uint(f);
  u += 0x7fffu + ((u >> 16) & 1u);
  return (unsigned short)(u >> 16);
}

__device__ __forceinline__ void gload16(const void* g, void* l) {
  __builtin_amdgcn_global_load_lds(
      (__attribute__((address_space(1))) void*)(void*)g,
      (__attribute__((address_space(3))) void*)l, 16, 0, 0);
}

// ---------------- weight prep: transposed combined matrices, bf16 hi/lo ----------------
__global__ void build_wt(const float* __restrict__ W, const float* __restrict__ b,
                         unsigned short* __restrict__ Wth, unsigned short* __restrict__ Wtl,
                         int has_box) {
  int k = threadIdx.x;          // 0..319
  int n = blockIdx.x;           // 0..511
  if (k >= 288) return;
  float v = 0.0f;
  if (n < 256) {                // P part
    if (k < 256)      v = W[k * 256 + n];
    else if (k < 263) v = has_box ? W[(512 + (k - 256)) * 256 + n] : 0.0f;
  } else {                      // Q part
    int n2 = n - 256;
    if (k < 256)      v = W[(256 + k) * 256 + n2] - W[k * 256 + n2];
    else if (k < 263) v = has_box ? -W[(512 + (k - 256)) * 256 + n2] : 0.0f;
    else if (k == 263) v = b[n2];
  }
  unsigned short hi = bf_hi_rne(v);
  float fh = __uint_as_float((unsigned int)hi << 16);
  Wth[n * 288 + k] = hi;
  Wtl[n * 288 + k] = bf_hi_rne(v - fh);
}

__global__ void build_wtg(const float* __restrict__ Wg, const float* __restrict__ bg,
                          unsigned short* __restrict__ Wth, unsigned short* __restrict__ Wtl) {
  int k = threadIdx.x;
  int n = blockIdx.x;
  if (k >= 288) return;
  float v = 0.0f;
  if (k < 263)       v = Wg[k * 256 + n];
  else if (k == 263) v = bg[n];
  unsigned short hi = bf_hi_rne(v);
  float fh = __uint_as_float((unsigned int)hi << 16);
  Wth[n * 288 + k] = hi;
  Wtl[n * 288 + k] = bf_hi_rne(v - fh);
}

// box hi/lo, padded to 32 cols: {rois[0..6], 1.0, 0 x 24}
__global__ void build_boxf16(const float* __restrict__ rois,
                             unsigned short* __restrict__ hi, unsigned short* __restrict__ lo) {
  int n = blockIdx.x * 256 + threadIdx.x;
  u16x8 h8 = (u16x8)0, l8 = (u16x8)0;
#pragma unroll
  for (int j = 0; j < 8; j++) {
    float v = (j < 7) ? rois[n * 7 + j] : 1.0f;
    unsigned short h = bf_hi_rne(v);
    h8[j] = h;
    l8[j] = bf_hi_rne(v - __uint_as_float((unsigned int)h << 16));
  }
  *(u16x8*)(hi + (size_t)n * 32) = h8;
  *(u16x8*)(lo + (size_t)n * 32) = l8;
  u16x8 z = (u16x8)0;
#pragma unroll
  for (int c = 1; c < 4; c++) {
    *(u16x8*)(hi + (size_t)n * 32 + c * 8) = z;
    *(u16x8*)(lo + (size_t)n * 32 + c * 8) = z;
  }
}

// fp32 -> bf16 hi/lo split (8 elems/thread)
__global__ void convert_split(const float* __restrict__ src,
                              unsigned short* __restrict__ hi, unsigned short* __restrict__ lo) {
  size_t i0 = ((size_t)blockIdx.x * 256 + threadIdx.x) * 8;
  float4 a = *(const float4*)(src + i0);
  float4 b = *(const float4*)(src + i0 + 4);
  float v[8] = {a.x, a.y, a.z, a.w, b.x, b.y, b.z, b.w};
  u16x8 h8, l8;
#pragma unroll
  for (int j = 0; j < 8; j++) {
    unsigned short h = bf_hi_rne(v[j]);
    h8[j] = h;
    l8[j] = bf_hi_rne(v[j] - __uint_as_float((unsigned int)h << 16));
  }
  *(u16x8*)(hi + i0) = h8;
  *(u16x8*)(lo + i0) = l8;
}

// ---------------- CSR build (counting sort by dst) ----------------
__global__ void hist_kernel(const int* __restrict__ dst, int* __restrict__ counts) {
  int e = blockIdx.x * 256 + threadIdx.x;
  atomicAdd(&counts[dst[e]], 1);
}

__global__ __launch_bounds__(1024) void scan_kernel(const int* __restrict__ counts,
                                                    int* __restrict__ offsets,
                                                    int* __restrict__ cursor) {
  __shared__ int ssum[1024];
  int t = threadIdx.x;
  int base = t * 16;
  int loc[16];
  int s = 0;
#pragma unroll
  for (int i = 0; i < 16; i++) { loc[i] = s; s += counts[base + i]; }
  ssum[t] = s;
  __syncthreads();
  for (int off = 1; off < 1024; off <<= 1) {
    int v = (t >= off) ? ssum[t - off] : 0;
    __syncthreads();
    ssum[t] += v;
    __syncthreads();
  }
  int excl = (t > 0) ? ssum[t - 1] : 0;
#pragma unroll
  for (int i = 0; i < 16; i++) {
    int o = excl + loc[i];
    offsets[base + i] = o;
    cursor[base + i]  = o;
  }
  if (t == 1023) offsets[NNODE] = excl + s;
}

__global__ void scatter_kernel(const int* __restrict__ src, const int* __restrict__ dst,
                               int* __restrict__ cursor, int* __restrict__ csr_src) {
  int e = blockIdx.x * 256 + threadIdx.x;
  int p = atomicAdd(&cursor[dst[e]], 1);
  csr_src[p] = src[e];
}

// ---------------- MFMA GEMM: out[NN,Nw] = [X(256)|box(7)|1|pad] @ Wt^T ----------------
// 128x128 tile, 4 waves (2x2 of 64x64), K = 9 steps of 32. All operands
// prepacked bf16 hi/lo -> staging is pure global_load_lds (16B), LDS linear
// [row][64B] (conflict-free: 4 lane-groups cover whole rows).
__global__ __launch_bounds__(256) void gemm_mfma(
    const unsigned short* __restrict__ Ah, const unsigned short* __restrict__ Al,
    const unsigned short* __restrict__ bxh, const unsigned short* __restrict__ bxl,
    const unsigned short* __restrict__ Wth, const unsigned short* __restrict__ Wtl,
    float* __restrict__ out, int Nw, int half_out) {
  __shared__ alignas(16) char lds[4 * 8192];   // Ahi | Alo | Bhi | Blo
  const int tid  = threadIdx.x;
  const int lane = tid & 63;
  const int wave = tid >> 6;
  const int wm = wave >> 1, wn = wave & 1;
  const int m0 = blockIdx.x * 128;
  const int n0 = blockIdx.y * 128;
  const int srow = tid >> 2;
  const int sc8  = (tid & 3) * 8;

  f32x4 acc[4][4];
#pragma unroll
  for (int i = 0; i < 4; i++)
#pragma unroll
    for (int j = 0; j < 4; j++) acc[i][j] = (f32x4)0.0f;

  const int kblk = lane >> 4;
  for (int kt = 0; kt < 9; kt++) {
    if (kt) __syncthreads();
#pragma unroll
    for (int p = 0; p < 2; p++) {
      int row = p * 64 + srow;
      const unsigned short *gah, *gal;
      if (kt < 8) {
        size_t o = (size_t)(m0 + row) * 256 + kt * 32 + sc8;
        gah = Ah + o; gal = Al + o;
      } else {
        size_t o = (size_t)(m0 + row) * 32 + sc8;
        gah = bxh + o; gal = bxl + o;
      }
      gload16(gah, lds + p * 4096 + tid * 16);
      gload16(gal, lds + 8192 + p * 4096 + tid * 16);
      size_t wo = (size_t)(n0 + row) * 288 + kt * 32 + sc8;
      gload16(Wth + wo, lds + 16384 + p * 4096 + tid * 16);
      gload16(Wtl + wo, lds + 24576 + p * 4096 + tid * 16);
    }
    __syncthreads();   // drains vmcnt (incl. global_load_lds) before ds_read

    bf16x8 ah[4], al[4];
#pragma unroll
    for (int i = 0; i < 4; i++) {
      int fm = wm * 64 + i * 16 + (lane & 15);
      int off = fm * 64 + 16 * kblk;
      ah[i] = *(const bf16x8*)(lds + off);
      al[i] = *(const bf16x8*)(lds + 8192 + off);
    }
#pragma unroll
    for (int j = 0; j < 4; j++) {
      int fn = wn * 64 + j * 16 + (lane & 15);
      int off = fn * 64 + 16 * kblk;
      bf16x8 bh = *(const bf16x8*)(lds + 16384 + off);
      bf16x8 bl = *(const bf16x8*)(lds + 24576 + off);
#pragma unroll
      for (int i = 0; i < 4; i++) {
        acc[i][j] = __builtin_amdgcn_mfma_f32_16x16x32_bf16(bh, ah[i], acc[i][j], 0, 0, 0);
        acc[i][j] = __builtin_amdgcn_mfma_f32_16x16x32_bf16(bh, al[i], acc[i][j], 0, 0, 0);
        acc[i][j] = __builtin_amdgcn_mfma_f32_16x16x32_bf16(bl, ah[i], acc[i][j], 0, 0, 0);
      }
    }
  }
#pragma unroll
  for (int i = 0; i < 4; i++) {
    int m = m0 + wm * 64 + i * 16 + (lane & 15);
#pragma unroll
    for (int j = 0; j < 4; j++) {
      int n = n0 + wn * 64 + j * 16 + (lane >> 4) * 4;
      if (half_out) {
        h16x4 o;
        o[0] = (_Float16)acc[i][j].x; o[1] = (_Float16)acc[i][j].y;
        o[2] = (_Float16)acc[i][j].z; o[3] = (_Float16)acc[i][j].w;
        *(h16x4*)((_Float16*)out + (size_t)m * Nw + n) = o;
      } else {
        *(f32x4*)(out + (size_t)m * Nw + n) = acc[i][j];
      }
    }
  }
}

// ---------------- edge pass v6: 2 nodes per wave CONCURRENT, half-wave/edge ----------------
// Lane (h = lane>>5, li = lane&31) owns fp16 cols [li*8, li*8+8). Per round:
// 8 x 1KB gathers in flight (4 per node). Activity flags wave-uniform.
constexpr int EPB = 8;   // nodes per block (4 waves x 2)
__global__ __launch_bounds__(256) void edge_pass(
    const _Float16* __restrict__ PQ,   // [NN][512] fp16 (P 0:256, Q 256:512)
    const int* __restrict__ offsets, const int* __restrict__ csr_src,
    float* __restrict__ M, float* __restrict__ psum, float* __restrict__ psq) {
  __shared__ float red[2][4][256];
  const int tid = threadIdx.x;
  const int wave = tid >> 6, lane = tid & 63;
  const int h = lane >> 5, li = lane & 31;
  const int c8 = li * 8;
  float sum[8] = {}, sq[8] = {};

  const int d0 = blockIdx.x * EPB + wave * 2;
  const int d1 = d0 + 1;
  int e0 = offsets[d0];
  const int end0 = offsets[d0 + 1];
  int e1 = offsets[d1];
  const int end1 = offsets[d1 + 1];

  h16x8 q0v = *(const h16x8*)(PQ + (size_t)d0 * 512 + 256 + c8);
  h16x8 q1v = *(const h16x8*)(PQ + (size_t)d1 * 512 + 256 + c8);
  float q0[8], q1[8], mx0[8], mx1[8];
#pragma unroll
  for (int j = 0; j < 8; j++) {
    q0[j] = (float)q0v[j]; q1[j] = (float)q1v[j];
    mx0[j] = -INFINITY;    mx1[j] = -INFINITY;
  }

  while (e0 < end0 || e1 < end1) {
    const bool a0 = e0 < end0, a1 = e1 < end1;   // wave-uniform
    int i0[4], i1[4];
    if (a0) {
#pragma unroll
      for (int i = 0; i < 4; i++) {
        int ei = e0 + 2 * i + h;
        i0[i] = csr_src[ei < end0 ? ei : end0 - 1];   // clamped dup (max-neutral)
      }
    }
    if (a1) {
#pragma unroll
      for (int i = 0; i < 4; i++) {
        int ei = e1 + 2 * i + h;
        i1[i] = csr_src[ei < end1 ? ei : end1 - 1];
      }
    }
    h16x8 p0[4], p1[4];
    if (a0) {
#pragma unroll
      for (int i = 0; i < 4; i++)
        p0[i] = *(const h16x8*)(PQ + (size_t)i0[i] * 512 + c8);
    }
    if (a1) {
#pragma unroll
      for (int i = 0; i < 4; i++)
        p1[i] = *(const h16x8*)(PQ + (size_t)i1[i] * 512 + c8);
    }

#define PROC_NODE(P, Q, MX, EE, END)                                        \
    {                                                                       \
      const int nl = (END) - (EE);                                          \
      if (nl >= 8) {                                                        \
        _Pragma("unroll")                                                   \
        for (int i = 0; i < 4; i++)                                         \
          _Pragma("unroll")                                                 \
          for (int j = 0; j < 8; j++) {                                     \
            float hh = (float)P[i][j] + Q[j];                               \
            MX[j] = fmaxf(MX[j], hh);                                       \
            sum[j] += hh; sq[j] = fmaf(hh, hh, sq[j]);                      \
          }                                                                 \
      } else {                                                              \
        _Pragma("unroll")                                                   \
        for (int i = 0; i < 4; i++) {                                       \
          const bool live = (2 * i + h) < nl;                               \
          _Pragma("unroll")                                                 \
          for (int j = 0; j < 8; j++) {                                     \
            float hh = (float)P[i][j] + Q[j];                               \
            MX[j] = fmaxf(MX[j], hh);                                       \
            float z = live ? hh : 0.f;                                      \
            sum[j] += z; sq[j] = fmaf(z, z, sq[j]);                         \
          }                                                                 \
        }                                                                   \
      }                                                                     \
    }

    if (a0) { PROC_NODE(p0, q0, mx0, e0, end0); e0 += 8; }
    if (a1) { PROC_NODE(p1, q1, mx1, e1, end1); e1 += 8; }
#undef PROC_NODE
  }

  // combine the two half-wave edge streams (disjoint edges, same node)
#pragma unroll
  for (int j = 0; j < 8; j++) {
    mx0[j] = fmaxf(mx0[j], __shfl_xor(mx0[j], 32));
    mx1[j] = fmaxf(mx1[j], __shfl_xor(mx1[j], 32));
  }
  float4 o0 = (h == 0) ? make_float4(mx0[0], mx0[1], mx0[2], mx0[3])
                       : make_float4(mx0[4], mx0[5], mx0[6], mx0[7]);
  float4 o1 = (h == 0) ? make_float4(mx1[0], mx1[1], mx1[2], mx1[3])
                       : make_float4(mx1[4], mx1[5], mx1[6], mx1[7]);
  *(float4*)(M + (size_t)d0 * 256 + c8 + h * 4) = o0;
  *(float4*)(M + (size_t)d1 * 256 + c8 + h * 4) = o1;

  // stats: fold halves, per-wave LDS slot, one atomic per column per block
#pragma unroll
  for (int j = 0; j < 8; j++) {
    sum[j] += __shfl_xor(sum[j], 32);
    sq[j]  += __shfl_xor(sq[j], 32);
  }
  if (h == 0) {
    *(float4*)&red[0][wave][c8]     = make_float4(sum[0], sum[1], sum[2], sum[3]);
    *(float4*)&red[0][wave][c8 + 4] = make_float4(sum[4], sum[5], sum[6], sum[7]);
    *(float4*)&red[1][wave][c8]     = make_float4(sq[0], sq[1], sq[2], sq[3]);
    *(float4*)&red[1][wave][c8 + 4] = make_float4(sq[4], sq[5], sq[6], sq[7]);
  }
  __syncthreads();
  int c = tid;
  float ts = red[0][0][c] + red[0][1][c] + red[0][2][c] + red[0][3][c];
  float tq = red[1][0][c] + red[1][1][c] + red[1][2][c] + red[1][3][c];
  atomicAdd(&psum[c], ts);
  atomicAdd(&psq[c], tq);
}

// ---------------- BN stats over dense rows (for x0) ----------------
__global__ void stats_dense(const float* __restrict__ H,
                            float* __restrict__ psum, float* __restrict__ psq) {
  int c  = threadIdx.x;
  int r0 = blockIdx.x * 16;
  float sum = 0.f, sq = 0.f;
  for (int r = r0; r < r0 + 16; r++) {
    float h = H[r * CD + c];
    sum += h;
    sq  += h * h;
  }
  atomicAdd(&psum[c], sum);
  atomicAdd(&psq[c], sq);
}

__global__ void finalize_stats(const float* __restrict__ psum, const float* __restrict__ psq,
                               float invcount, float* __restrict__ mu, float* __restrict__ rstd) {
  int c = threadIdx.x;
  float m = psum[c] * invcount;
  float v = psq[c] * invcount - m * m;
  v = fmaxf(v, 0.0f);
  mu[c]   = m;
  rstd[c] = 1.0f / sqrtf(v + EPSB);
}

// normalize + ReLU; writes final out column block AND (optionally) the bf16
// hi/lo split consumed by the NEXT layer's GEMM A-staging.
__global__ void normalize_write(const float* __restrict__ H, const int* __restrict__ counts,
                                const float* __restrict__ mu, const float* __restrict__ rstd,
                                const float* __restrict__ gamma, const float* __restrict__ beta,
                                float* __restrict__ out, int col0,
                                unsigned short* __restrict__ xh, unsigned short* __restrict__ xl) {
  int c  = threadIdx.x;
  int n0 = blockIdx.x * 8;
  float mc = mu[c], rc = rstd[c], gc = gamma[c], bc = beta[c];
  for (int n = n0; n < n0 + 8; n++) {
    float v = 0.0f;
    if (!counts || counts[n] != 0) {
      float h = H[n * CD + c];
      v = fmaxf((h - mc) * rc * gc + bc, 0.0f);
    }
    out[n * 1024 + col0 + c] = v;
    if (xh) {
      unsigned short hv = bf_hi_rne(v);
      xh[(size_t)n * 256 + c] = hv;
      xl[(size_t)n * 256 + c] = bf_hi_rne(v - __uint_as_float((unsigned int)hv << 16));
    }
  }
}

// ---------------- launch ----------------
extern "C" void kernel_launch(void* const* d_in, const int* in_sizes, int n_in,
                              void* d_out, int out_size, void* d_ws, size_t ws_size,
                              hipStream_t stream) {
  const float* pf    = (const float*)d_in[0];
  const float* rois  = (const float*)d_in[1];
  const int*   esrc  = (const int*)d_in[2];
  const int*   edst  = (const int*)d_in[3];
  const float* Wg    = (const float*)d_in[4];
  const float* bg    = (const float*)d_in[5];
  const float* gg    = (const float*)d_in[6];
  const float* betag = (const float*)d_in[7];
  const float* Wl[3]  = {(const float*)d_in[8],  (const float*)d_in[12], (const float*)d_in[16]};
  const float* bl[3]  = {(const float*)d_in[9],  (const float*)d_in[13], (const float*)d_in[17]};
  const float* gl[3]  = {(const float*)d_in[10], (const float*)d_in[14], (const float*)d_in[18]};
  const float* bel[3] = {(const float*)d_in[11], (const float*)d_in[15], (const float*)d_in[19]};
  float* out = (float*)d_out;

  // workspace layout (~53 MB)
  float* ws    = (float*)d_ws;
  _Float16* PQ = (_Float16*)ws;                       // NN*512 fp16 = 16 MB
  float* Mbuf  = ws + (size_t)NNODE * 256;            // NN*256 f32 = 16 MB
  float* psum  = Mbuf + (size_t)NNODE * CD;
  float* psq   = psum + CD;
  float* mu    = psq + CD;
  float* rstd  = mu + CD;
  unsigned short* Ah = (unsigned short*)(rstd + CD);  // NN*256 bf16-hi (8 MB)
  unsigned short* Al = Ah + (size_t)NNODE * 256;      // NN*256 bf16-lo
  unsigned short* bxh = Al + (size_t)NNODE * 256;     // NN*32
  unsigned short* bxl = bxh + (size_t)NNODE * 32;
  unsigned short* wt  = bxl + (size_t)NNODE * 32;     // 3 layers x (hi|lo)[512*288]
  unsigned short* wtg_h = wt + 3 * 2 * 512 * 288;
  unsigned short* wtg_l = wtg_h + 256 * 288;
  int* counts  = (int*)(wtg_l + 256 * 288);
  int* offsets = counts + NNODE;
  int* cursor  = offsets + NNODE + 1;
  int* csr     = cursor + NNODE;

  hipMemsetAsync(counts, 0, NNODE * sizeof(int), stream);
  build_boxf16<<<NNODE / 256, 256, 0, stream>>>(rois, bxh, bxl);
  convert_split<<<NNODE * CD / (256 * 8), 256, 0, stream>>>(pf, Ah, Al);
  build_wtg<<<256, 320, 0, stream>>>(Wg, bg, wtg_h, wtg_l);
  for (int l = 0; l < 3; l++)
    build_wt<<<512, 320, 0, stream>>>(Wl[l], bl[l],
                                      wt + l * 2 * 512 * 288,
                                      wt + l * 2 * 512 * 288 + 512 * 288,
                                      l == 0 ? 1 : 0);
  hist_kernel<<<NEDGE / 256, 256, 0, stream>>>(edst, counts);
  scan_kernel<<<1, 1024, 0, stream>>>(counts, offsets, cursor);
  scatter_kernel<<<NEDGE / 256, 256, 0, stream>>>(esrc, edst, cursor, csr);

  // x0 = BN-ReLU([pf|box|1] @ Wg+bg)  (fp32 out; Ah/Al refilled with x0 after)
  hipMemsetAsync(psum, 0, 2 * CD * sizeof(float), stream);
  {
    dim3 g(NNODE / 128, 2);
    gemm_mfma<<<g, 256, 0, stream>>>(Ah, Al, bxh, bxl, wtg_h, wtg_l, Mbuf, 256, 0);
  }
  stats_dense<<<NNODE / 16, 256, 0, stream>>>(Mbuf, psum, psq);
  finalize_stats<<<1, 256, 0, stream>>>(psum, psq, 1.0f / NNODE, mu, rstd);
  normalize_write<<<NNODE / 8, 256, 0, stream>>>(Mbuf, nullptr, mu, rstd, gg, betag,
                                                 out, 0, Ah, Al);

  // three EdgeConv layers
  for (int l = 0; l < 3; l++) {
    dim3 g(NNODE / 128, 4);
    gemm_mfma<<<g, 256, 0, stream>>>(Ah, Al, bxh, bxl,
                                     wt + l * 2 * 512 * 288,
                                     wt + l * 2 * 512 * 288 + 512 * 288,
                                     (float*)PQ, 512, 1);
    hipMemsetAsync(psum, 0, 2 * CD * sizeof(float), stream);
    edge_pass<<<NNODE / EPB, 256, 0, stream>>>(PQ, offsets, csr, Mbuf, psum, psq);
    finalize_stats<<<1, 256, 0, stream>>>(psum, psq, 1.0f / NEDGE, mu, rstd);
    normalize_write<<<NNODE / 8, 256, 0, stream>>>(Mbuf, counts, mu, rstd, gl[l], bel[l],
                                                   out, (l + 1) * CD,
                                                   l < 2 ? Ah : nullptr,
                                                   l < 2 ? Al : nullptr);
  }
}

// Round 7
// 460.424 us; speedup vs baseline: 1.3746x; 1.0754x over previous
//
#include <hip/hip_runtime.h>
#include <hip/hip_bf16.h>
#include <hip/hip_fp16.h>
#include <math.h>
#include <stdint.h>

// GNN relation module, restructured:
//   h_e = P[src] + Q[dst]  (node-level GEMMs instead of edge-level)
//   P = [x|box|1] @ [Wa; Wc; 0],  Q = [x|box|1] @ [Wb-Wa; -Wc; b]
// GEMMs: SINGLE-term bf16 MFMA (error ~4e-3 << 0.113 threshold; the old
// 3-term hi/lo split was over-conservative). A pre-split to bf16 in the
// epilogue of the previous layer; staging is pure global_load_lds DMA.
// PQ stored fp16. edge_pass v7: two-bank software pipeline — gathers for
// round r+1 issued BEFORE processing round r (latency hides under VALU);
// packed-fp16 add/max; 8 waves/block keeps stats-atomic fan-in at 2048.
// segment_max commutes with BN+ReLU (slope rstd*gamma >= 0): max raw h per
// dst node, then normalize node maxima. Empty segments via counts==0.

constexpr int NNODE = 16384;
constexpr int NEDGE = 262144;
constexpr int CD    = 256;
constexpr float EPSB = 1e-5f;

typedef __attribute__((ext_vector_type(8))) short bf16x8;
typedef __attribute__((ext_vector_type(8))) unsigned short u16x8;
typedef __attribute__((ext_vector_type(4))) float f32x4;
typedef __attribute__((ext_vector_type(4))) _Float16 h16x4;
typedef __attribute__((ext_vector_type(8))) _Float16 h16x8;
typedef __attribute__((ext_vector_type(2))) _Float16 h16x2;

__device__ inline unsigned short bf_hi_rne(float f) {
  unsigned int u = __float_as_uint(f);
  u += 0x7fffu + ((u >> 16) & 1u);
  return (unsigned short)(u >> 16);
}

__device__ __forceinline__ void gload16(const void* g, void* l) {
  __builtin_amdgcn_global_load_lds(
      (__attribute__((address_space(1))) void*)(void*)g,
      (__attribute__((address_space(3))) void*)l, 16, 0, 0);
}

// ---------------- weight prep: transposed combined matrices, bf16 ----------------
__global__ void build_wt(const float* __restrict__ W, const float* __restrict__ b,
                         unsigned short* __restrict__ Wth, int has_box) {
  int k = threadIdx.x;          // 0..319
  int n = blockIdx.x;           // 0..511
  if (k >= 288) return;
  float v = 0.0f;
  if (n < 256) {                // P part
    if (k < 256)      v = W[k * 256 + n];
    else if (k < 263) v = has_box ? W[(512 + (k - 256)) * 256 + n] : 0.0f;
  } else {                      // Q part
    int n2 = n - 256;
    if (k < 256)      v = W[(256 + k) * 256 + n2] - W[k * 256 + n2];
    else if (k < 263) v = has_box ? -W[(512 + (k - 256)) * 256 + n2] : 0.0f;
    else if (k == 263) v = b[n2];
  }
  Wth[n * 288 + k] = bf_hi_rne(v);
}

__global__ void build_wtg(const float* __restrict__ Wg, const float* __restrict__ bg,
                          unsigned short* __restrict__ Wth) {
  int k = threadIdx.x;
  int n = blockIdx.x;
  if (k >= 288) return;
  float v = 0.0f;
  if (k < 263)       v = Wg[k * 256 + n];
  else if (k == 263) v = bg[n];
  Wth[n * 288 + k] = bf_hi_rne(v);
}

// box bf16, padded to 32 cols: {rois[0..6], 1.0, 0 x 24}
__global__ void build_boxf16(const float* __restrict__ rois,
                             unsigned short* __restrict__ hi) {
  int n = blockIdx.x * 256 + threadIdx.x;
  u16x8 h8 = (u16x8)0;
#pragma unroll
  for (int j = 0; j < 8; j++) {
    float v = (j < 7) ? rois[n * 7 + j] : 1.0f;
    h8[j] = bf_hi_rne(v);
  }
  *(u16x8*)(hi + (size_t)n * 32) = h8;
  u16x8 z = (u16x8)0;
#pragma unroll
  for (int c = 1; c < 4; c++) *(u16x8*)(hi + (size_t)n * 32 + c * 8) = z;
}

// fp32 -> bf16 (8 elems/thread)
__global__ void convert_split(const float* __restrict__ src,
                              unsigned short* __restrict__ hi) {
  size_t i0 = ((size_t)blockIdx.x * 256 + threadIdx.x) * 8;
  float4 a = *(const float4*)(src + i0);
  float4 b = *(const float4*)(src + i0 + 4);
  float v[8] = {a.x, a.y, a.z, a.w, b.x, b.y, b.z, b.w};
  u16x8 h8;
#pragma unroll
  for (int j = 0; j < 8; j++) h8[j] = bf_hi_rne(v[j]);
  *(u16x8*)(hi + i0) = h8;
}

// ---------------- CSR build (counting sort by dst) ----------------
__global__ void hist_kernel(const int* __restrict__ dst, int* __restrict__ counts) {
  int e = blockIdx.x * 256 + threadIdx.x;
  atomicAdd(&counts[dst[e]], 1);
}

__global__ __launch_bounds__(1024) void scan_kernel(const int* __restrict__ counts,
                                                    int* __restrict__ offsets,
                                                    int* __restrict__ cursor) {
  __shared__ int ssum[1024];
  int t = threadIdx.x;
  int base = t * 16;
  int loc[16];
  int s = 0;
#pragma unroll
  for (int i = 0; i < 16; i++) { loc[i] = s; s += counts[base + i]; }
  ssum[t] = s;
  __syncthreads();
  for (int off = 1; off < 1024; off <<= 1) {
    int v = (t >= off) ? ssum[t - off] : 0;
    __syncthreads();
    ssum[t] += v;
    __syncthreads();
  }
  int excl = (t > 0) ? ssum[t - 1] : 0;
#pragma unroll
  for (int i = 0; i < 16; i++) {
    int o = excl + loc[i];
    offsets[base + i] = o;
    cursor[base + i]  = o;
  }
  if (t == 1023) offsets[NNODE] = excl + s;
}

__global__ void scatter_kernel(const int* __restrict__ src, const int* __restrict__ dst,
                               int* __restrict__ cursor, int* __restrict__ csr_src) {
  int e = blockIdx.x * 256 + threadIdx.x;
  int p = atomicAdd(&cursor[dst[e]], 1);
  csr_src[p] = src[e];
}

// ---------------- MFMA GEMM: out[NN,Nw] = [X(256)|box(7)|1|pad] @ Wt^T ----------------
// 128x128 tile, 4 waves (2x2 of 64x64), K = 9 steps of 32. Single-term bf16.
// Staging: pure global_load_lds (16B). LDS linear [row][64B] (conflict-free:
// the 4 lane-groups of a wave cover whole rows).
__global__ __launch_bounds__(256) void gemm_mfma(
    const unsigned short* __restrict__ Ah,
    const unsigned short* __restrict__ bxh,
    const unsigned short* __restrict__ Wth,
    float* __restrict__ out, int Nw, int half_out) {
  __shared__ alignas(16) char lds[2 * 8192];   // A | B, 128 rows x 64B each
  const int tid  = threadIdx.x;
  const int lane = tid & 63;
  const int wave = tid >> 6;
  const int wm = wave >> 1, wn = wave & 1;
  const int m0 = blockIdx.x * 128;
  const int n0 = blockIdx.y * 128;
  const int srow = tid >> 2;
  const int sc8  = (tid & 3) * 8;

  f32x4 acc[4][4];
#pragma unroll
  for (int i = 0; i < 4; i++)
#pragma unroll
    for (int j = 0; j < 4; j++) acc[i][j] = (f32x4)0.0f;

  const int kblk = lane >> 4;
  for (int kt = 0; kt < 9; kt++) {
    if (kt) __syncthreads();
#pragma unroll
    for (int p = 0; p < 2; p++) {
      int row = p * 64 + srow;
      const unsigned short* ga =
          (kt < 8) ? Ah + (size_t)(m0 + row) * 256 + kt * 32 + sc8
                   : bxh + (size_t)(m0 + row) * 32 + sc8;
      gload16(ga, lds + p * 4096 + tid * 16);
      gload16(Wth + (size_t)(n0 + row) * 288 + kt * 32 + sc8,
              lds + 8192 + p * 4096 + tid * 16);
    }
    __syncthreads();   // drains vmcnt (incl. global_load_lds) before ds_read

    bf16x8 ah[4];
#pragma unroll
    for (int i = 0; i < 4; i++) {
      int fm = wm * 64 + i * 16 + (lane & 15);
      ah[i] = *(const bf16x8*)(lds + fm * 64 + 16 * kblk);
    }
#pragma unroll
    for (int j = 0; j < 4; j++) {
      int fn = wn * 64 + j * 16 + (lane & 15);
      bf16x8 bh = *(const bf16x8*)(lds + 8192 + fn * 64 + 16 * kblk);
#pragma unroll
      for (int i = 0; i < 4; i++)
        acc[i][j] = __builtin_amdgcn_mfma_f32_16x16x32_bf16(bh, ah[i], acc[i][j], 0, 0, 0);
    }
  }
#pragma unroll
  for (int i = 0; i < 4; i++) {
    int m = m0 + wm * 64 + i * 16 + (lane & 15);
#pragma unroll
    for (int j = 0; j < 4; j++) {
      int n = n0 + wn * 64 + j * 16 + (lane >> 4) * 4;
      if (half_out) {
        h16x4 o;
        o[0] = (_Float16)acc[i][j].x; o[1] = (_Float16)acc[i][j].y;
        o[2] = (_Float16)acc[i][j].z; o[3] = (_Float16)acc[i][j].w;
        *(h16x4*)((_Float16*)out + (size_t)m * Nw + n) = o;
      } else {
        *(f32x4*)(out + (size_t)m * Nw + n) = acc[i][j];
      }
    }
  }
}

// ---------------- edge pass v7: 1 node/wave, two-bank pipelined gathers ----------------
// Lane (h = lane>>5, li = lane&31) owns fp16 cols [li*8, li*8+8). Round =
// 8 edges via 4 x h16x8 gathers (1 KB each). Bank B's gathers are in flight
// while bank A is processed (packed-fp16 add/max; fp32 sums).
__global__ __launch_bounds__(512) void edge_pass(
    const _Float16* __restrict__ PQ,   // [NN][512] fp16 (P 0:256, Q 256:512)
    const int* __restrict__ offsets, const int* __restrict__ csr_src,
    float* __restrict__ M, float* __restrict__ psum, float* __restrict__ psq) {
  __shared__ float red[2][8][256];
  const int tid = threadIdx.x;
  const int wave = tid >> 6, lane = tid & 63;
  const int h = lane >> 5, li = lane & 31;
  const int c8 = li * 8;
  float sum[8] = {}, sq[8] = {};

  const int d = blockIdx.x * 8 + wave;
  const int beg = offsets[d], end = offsets[d + 1];
  const bool any = beg < end;

  if (any) {
    h16x8 qv = *(const h16x8*)(PQ + (size_t)d * 512 + 256 + c8);
    h16x2 q2[4], mx2[4];
    _Float16 NINF = (_Float16)(-INFINITY);
#pragma unroll
    for (int jj = 0; jj < 4; jj++) {
      q2[jj][0] = qv[2 * jj]; q2[jj][1] = qv[2 * jj + 1];
      mx2[jj][0] = NINF;      mx2[jj][1] = NINF;
    }

#define LOADIDX(I, E)                                                     \
    _Pragma("unroll") for (int i = 0; i < 4; i++) {                       \
      int ei = (E) + 2 * i + h;                                           \
      I[i] = csr_src[ei < end ? ei : end - 1];  /* clamped dup */         \
    }
#define GATHER(P, I)                                                      \
    _Pragma("unroll") for (int i = 0; i < 4; i++)                         \
      P[i] = *(const h16x8*)(PQ + (size_t)I[i] * 512 + c8);
#define PROC(P, E)                                                        \
    {                                                                     \
      const int nl = end - (E);                                           \
      if (nl >= 8) {                                                      \
        _Pragma("unroll") for (int i = 0; i < 4; i++)                     \
          _Pragma("unroll") for (int jj = 0; jj < 4; jj++) {              \
            h16x2 pp; pp[0] = P[i][2 * jj]; pp[1] = P[i][2 * jj + 1];     \
            h16x2 hh = pp + q2[jj];            /* v_pk_add_f16 */         \
            mx2[jj] = __builtin_elementwise_max(mx2[jj], hh);             \
            float h0 = (float)hh[0], h1 = (float)hh[1];                   \
            sum[2 * jj] += h0; sum[2 * jj + 1] += h1;                     \
            sq[2 * jj] = fmaf(h0, h0, sq[2 * jj]);                        \
            sq[2 * jj + 1] = fmaf(h1, h1, sq[2 * jj + 1]);                \
          }                                                               \
      } else {                                                            \
        _Pragma("unroll") for (int i = 0; i < 4; i++) {                   \
          const bool live = (2 * i + h) < nl;                             \
          _Pragma("unroll") for (int jj = 0; jj < 4; jj++) {              \
            h16x2 pp; pp[0] = P[i][2 * jj]; pp[1] = P[i][2 * jj + 1];     \
            h16x2 hh = pp + q2[jj];                                       \
            mx2[jj] = __builtin_elementwise_max(mx2[jj], hh);             \
            float h0 = (float)hh[0], h1 = (float)hh[1];                   \
            float z0 = live ? h0 : 0.f, z1 = live ? h1 : 0.f;             \
            sum[2 * jj] += z0; sum[2 * jj + 1] += z1;                     \
            sq[2 * jj] = fmaf(z0, z0, sq[2 * jj]);                        \
            sq[2 * jj + 1] = fmaf(z1, z1, sq[2 * jj + 1]);                \
          }                                                               \
        }                                                                 \
      }                                                                   \
    }

    int iA[4], iB[4];
    h16x8 pA[4], pB[4];
    LOADIDX(iA, beg);
    GATHER(pA, iA);
    if (beg + 8 < end) { LOADIDX(iB, beg + 8); GATHER(pB, iB); }
    int e = beg;
    while (true) {
      PROC(pA, e);
      if (e + 16 < end) { LOADIDX(iA, e + 16); GATHER(pA, iA); }
      e += 8;
      if (e >= end) break;
      PROC(pB, e);
      if (e + 16 < end) { LOADIDX(iB, e + 16); GATHER(pB, iB); }
      e += 8;
      if (e >= end) break;
    }
#undef LOADIDX
#undef GATHER
#undef PROC

    float mxf[8];
#pragma unroll
    for (int jj = 0; jj < 4; jj++) {
      mxf[2 * jj]     = (float)mx2[jj][0];
      mxf[2 * jj + 1] = (float)mx2[jj][1];
    }
#pragma unroll
    for (int j = 0; j < 8; j++)
      mxf[j] = fmaxf(mxf[j], __shfl_xor(mxf[j], 32));
    float4 o = (h == 0) ? make_float4(mxf[0], mxf[1], mxf[2], mxf[3])
                        : make_float4(mxf[4], mxf[5], mxf[6], mxf[7]);
    *(float4*)(M + (size_t)d * 256 + c8 + h * 4) = o;
  }

  // stats: fold halves, per-wave LDS slot, one atomic per column per block
#pragma unroll
  for (int j = 0; j < 8; j++) {
    sum[j] += __shfl_xor(sum[j], 32);
    sq[j]  += __shfl_xor(sq[j], 32);
  }
  if (h == 0) {
    *(float4*)&red[0][wave][c8]     = make_float4(sum[0], sum[1], sum[2], sum[3]);
    *(float4*)&red[0][wave][c8 + 4] = make_float4(sum[4], sum[5], sum[6], sum[7]);
    *(float4*)&red[1][wave][c8]     = make_float4(sq[0], sq[1], sq[2], sq[3]);
    *(float4*)&red[1][wave][c8 + 4] = make_float4(sq[4], sq[5], sq[6], sq[7]);
  }
  __syncthreads();
  if (tid < 256) {
    float ts = 0.f, tq = 0.f;
#pragma unroll
    for (int w = 0; w < 8; w++) { ts += red[0][w][tid]; tq += red[1][w][tid]; }
    atomicAdd(&psum[tid], ts);
    atomicAdd(&psq[tid], tq);
  }
}

// ---------------- BN stats over dense rows (for x0) ----------------
__global__ void stats_dense(const float* __restrict__ H,
                            float* __restrict__ psum, float* __restrict__ psq) {
  int c  = threadIdx.x;
  int r0 = blockIdx.x * 16;
  float sum = 0.f, sq = 0.f;
  for (int r = r0; r < r0 + 16; r++) {
    float h = H[r * CD + c];
    sum += h;
    sq  += h * h;
  }
  atomicAdd(&psum[c], sum);
  atomicAdd(&psq[c], sq);
}

__global__ void finalize_stats(const float* __restrict__ psum, const float* __restrict__ psq,
                               float invcount, float* __restrict__ mu, float* __restrict__ rstd) {
  int c = threadIdx.x;
  float m = psum[c] * invcount;
  float v = psq[c] * invcount - m * m;
  v = fmaxf(v, 0.0f);
  mu[c]   = m;
  rstd[c] = 1.0f / sqrtf(v + EPSB);
}

// normalize + ReLU; writes final out column block AND (optionally) the bf16
// copy consumed by the NEXT layer's GEMM A-staging.
__global__ void normalize_write(const float* __restrict__ H, const int* __restrict__ counts,
                                const float* __restrict__ mu, const float* __restrict__ rstd,
                                const float* __restrict__ gamma, const float* __restrict__ beta,
                                float* __restrict__ out, int col0,
                                unsigned short* __restrict__ xh) {
  int c  = threadIdx.x;
  int n0 = blockIdx.x * 8;
  float mc = mu[c], rc = rstd[c], gc = gamma[c], bc = beta[c];
  for (int n = n0; n < n0 + 8; n++) {
    float v = 0.0f;
    if (!counts || counts[n] != 0) {
      float h = H[n * CD + c];
      v = fmaxf((h - mc) * rc * gc + bc, 0.0f);
    }
    out[n * 1024 + col0 + c] = v;
    if (xh) xh[(size_t)n * 256 + c] = bf_hi_rne(v);
  }
}

// ---------------- launch ----------------
extern "C" void kernel_launch(void* const* d_in, const int* in_sizes, int n_in,
                              void* d_out, int out_size, void* d_ws, size_t ws_size,
                              hipStream_t stream) {
  const float* pf    = (const float*)d_in[0];
  const float* rois  = (const float*)d_in[1];
  const int*   esrc  = (const int*)d_in[2];
  const int*   edst  = (const int*)d_in[3];
  const float* Wg    = (const float*)d_in[4];
  const float* bg    = (const float*)d_in[5];
  const float* gg    = (const float*)d_in[6];
  const float* betag = (const float*)d_in[7];
  const float* Wl[3]  = {(const float*)d_in[8],  (const float*)d_in[12], (const float*)d_in[16]};
  const float* bl[3]  = {(const float*)d_in[9],  (const float*)d_in[13], (const float*)d_in[17]};
  const float* gl[3]  = {(const float*)d_in[10], (const float*)d_in[14], (const float*)d_in[18]};
  const float* bel[3] = {(const float*)d_in[11], (const float*)d_in[15], (const float*)d_in[19]};
  float* out = (float*)d_out;

  // workspace layout (~44 MB)
  float* ws    = (float*)d_ws;
  _Float16* PQ = (_Float16*)ws;                       // NN*512 fp16 = 16 MB
  float* Mbuf  = ws + (size_t)NNODE * 256;            // NN*256 f32 = 16 MB
  float* psum  = Mbuf + (size_t)NNODE * CD;
  float* psq   = psum + CD;
  float* mu    = psq + CD;
  float* rstd  = mu + CD;
  unsigned short* Ah  = (unsigned short*)(rstd + CD); // NN*256 bf16 (8 MB)
  unsigned short* bxh = Ah + (size_t)NNODE * 256;     // NN*32
  unsigned short* wt  = bxh + (size_t)NNODE * 32;     // 3 layers x [512*288]
  unsigned short* wtg = wt + 3 * 512 * 288;           // [256*288]
  int* counts  = (int*)(wtg + 256 * 288);
  int* offsets = counts + NNODE;
  int* cursor  = offsets + NNODE + 1;
  int* csr     = cursor + NNODE;

  hipMemsetAsync(counts, 0, NNODE * sizeof(int), stream);
  build_boxf16<<<NNODE / 256, 256, 0, stream>>>(rois, bxh);
  convert_split<<<NNODE * CD / (256 * 8), 256, 0, stream>>>(pf, Ah);
  build_wtg<<<256, 320, 0, stream>>>(Wg, bg, wtg);
  for (int l = 0; l < 3; l++)
    build_wt<<<512, 320, 0, stream>>>(Wl[l], bl[l], wt + l * 512 * 288, l == 0 ? 1 : 0);
  hist_kernel<<<NEDGE / 256, 256, 0, stream>>>(edst, counts);
  scan_kernel<<<1, 1024, 0, stream>>>(counts, offsets, cursor);
  scatter_kernel<<<NEDGE / 256, 256, 0, stream>>>(esrc, edst, cursor, csr);

  // x0 = BN-ReLU([pf|box|1] @ Wg+bg)  (fp32 out; Ah refilled with x0 after)
  hipMemsetAsync(psum, 0, 2 * CD * sizeof(float), stream);
  {
    dim3 g(NNODE / 128, 2);
    gemm_mfma<<<g, 256, 0, stream>>>(Ah, bxh, wtg, Mbuf, 256, 0);
  }
  stats_dense<<<NNODE / 16, 256, 0, stream>>>(Mbuf, psum, psq);
  finalize_stats<<<1, 256, 0, stream>>>(psum, psq, 1.0f / NNODE, mu, rstd);
  normalize_write<<<NNODE / 8, 256, 0, stream>>>(Mbuf, nullptr, mu, rstd, gg, betag,
                                                 out, 0, Ah);

  // three EdgeConv layers
  for (int l = 0; l < 3; l++) {
    dim3 g(NNODE / 128, 4);
    gemm_mfma<<<g, 256, 0, stream>>>(Ah, bxh, wt + l * 512 * 288, (float*)PQ, 512, 1);
    hipMemsetAsync(psum, 0, 2 * CD * sizeof(float), stream);
    edge_pass<<<NNODE / 8, 512, 0, stream>>>(PQ, offsets, csr, Mbuf, psum, psq);
    finalize_stats<<<1, 256, 0, stream>>>(psum, psq, 1.0f / NEDGE, mu, rstd);
    normalize_write<<<NNODE / 8, 256, 0, stream>>>(Mbuf, counts, mu, rstd, gl[l], bel[l],
                                                   out, (l + 1) * CD,
                                                   l < 2 ? Ah : nullptr);
  }
}